// Round 13
// baseline (112.963 us; speedup 1.0000x reference)
//
#include <hip/hip_runtime.h>
#include <hip/hip_cooperative_groups.h>
#include <stdint.h>

namespace cg = cooperative_groups;

#define BATCH 1024
#define DIM 768

typedef unsigned long long u64;
typedef __attribute__((ext_vector_type(8))) short short8;  // 8 bf16 = 4 VGPRs
typedef __attribute__((ext_vector_type(4))) float f32x4;

// Workspace layout (bytes):
//   [0]      int   tailcnt             (atomicExch-zeroed in phase P)
//   [4096]   float pmax[1024*4]        (16 KB) per-row per-chunk max
//   [20480]  float psum[1024*4]        (16 KB) per-row per-chunk sumexp
//   [36864]  float lval[1024]          (4 KB)  exact fp32 label logit per row
//   [49152]  ushort txtB[1024*768]     (1.5 MB) bf16, MFMA B-frag order
// B-frag order: off(col,k) = ((k>>5)*64 + (col>>4))*512 + ((k>>3)&3)*128
//                            + (col&15)*8 + (k&7)
#define WS_TAIL     0
#define WS_PMAX  4096
#define WS_PSUM 20480
#define WS_LVAL 36864
#define WS_TXTB 49152

__device__ __forceinline__ unsigned short to_bf16(float x) {
    unsigned int u = __float_as_uint(x);
    return (unsigned short)((u + 0x7FFFu + ((u >> 16) & 1u)) >> 16);  // RNE
}

// ---------------------------------------------------------------------------
// ONE cooperative kernel, 256 blocks x 1024 threads (1 block/CU guaranteed
// co-resident by the cooperative-launch contract -> grid.sync is
// deadlock-free by construction; vendor barrier handles cross-XCD
// visibility — this is the documented-correct form of what R2 attempted
// by hand and got wrong).
//
// Phase P: (a) block 0 zeroes tailcnt (atomicExch, coherent point);
//          (b) waves 0..5 convert txt group G = blockIdx*6 + wave into
//              txtB (same (G,lane)->address mapping as the R7 prep kernel
//              -> bit-identical bytes);
//          (c) all 16 waves stage A (img rows -> bf16 frag order, R7
//              verbatim).
// grid.sync()
// Phase G: R7 gemm_fused body verbatim: k-loop from txtB (contiguous 1 KB
//          B-frags), per-row chunk partials via atomicExch, float2-sig
//          labels + exact verify + fp32 label dot, counter-based
//          last-block combine. No hand-rolled spins anywhere.
// ---------------------------------------------------------------------------
__global__ __launch_bounds__(1024) void coop_kernel(
        const float* __restrict__ img, const float* __restrict__ txt,
        const float* __restrict__ scale_p, unsigned short* __restrict__ txtB,
        float* __restrict__ pmax, float* __restrict__ psum,
        float* __restrict__ lval, int* __restrict__ tailcnt,
        float* __restrict__ out) {
    __shared__ unsigned short Ahi[16 * DIM];   // 24 KB, A-frag order
    __shared__ float logitsS[16 * 260];        // 16.6 KB (+4 pad vs bank stride)
    __shared__ int isLast;
    __shared__ float part[16];

    const int tid  = threadIdx.x;
    const int wave = tid >> 6;
    const int lane = tid & 63;
    const int quad = lane >> 4;
    const int l15  = lane & 15;
    const int r0    = (blockIdx.x >> 2) * 16;
    const int chunk = blockIdx.x & 3;

    // ---- Phase P ----------------------------------------------------------
    if (blockIdx.x == 0 && tid == 0) atomicExch(tailcnt, 0);

    // txt -> bf16 B-frag order: wave w<6 handles group G = b*6 + w
    // (same (G,lane) writes as R7 prep -> bit-identical txtB)
    if (wave < 6) {
        const int G  = blockIdx.x * 6 + wave;
        const int tt = G / 24;        // col-tile 0..63
        const int g  = G - tt * 24;   // k-group 0..23
        const int col = tt * 16 + l15;
        const int k0  = g * 32 + quad * 8;
        const float4 va = *(const float4*)(txt + (size_t)col * DIM + k0);
        const float4 vb = *(const float4*)(txt + (size_t)col * DIM + k0 + 4);
        short8 hv = {(short)to_bf16(va.x), (short)to_bf16(va.y),
                     (short)to_bf16(va.z), (short)to_bf16(va.w),
                     (short)to_bf16(vb.x), (short)to_bf16(vb.y),
                     (short)to_bf16(vb.z), (short)to_bf16(vb.w)};
        *(short8*)(txtB + (size_t)(g * 64 + tt) * 512 + lane * 8) = hv;
    }

    // stage A: wave w converts img row r0+w into frag order (R7 verbatim)
    {
        const float* ir = img + (size_t)(r0 + wave) * DIM;
#pragma unroll
        for (int j = 0; j < 12; ++j) {
            const int k = lane + j * 64;
            Ahi[((k >> 3) * 16 + wave) * 8 + (k & 7)] = to_bf16(ir[k]);
        }
    }

    // ---- grid-wide barrier (vendor-correct cross-XCD visibility) ----------
    cg::this_grid().sync();

    // ---- Phase G (R7 gemm_fused verbatim) ---------------------------------
    const int t = chunk * 16 + wave;
    const int foff = quad * 128 + l15 * 8;
    f32x4 acc = {0.f, 0.f, 0.f, 0.f};
#pragma unroll
    for (int kk = 0; kk < 24; ++kk) {
        const short8 a = *(const short8*)&Ahi[kk * 512 + foff];
        const short8 b = *(const short8*)(txtB + (size_t)(kk * 64 + t) * 512 + foff);
        acc = __builtin_amdgcn_mfma_f32_16x16x32_bf16(a, b, acc, 0, 0, 0);
    }

    // C layout: col = l15, row = quad*4 + r  [verified, absmax 0.0]
    const float scale = scale_p[0];
#pragma unroll
    for (int r = 0; r < 4; ++r)
        logitsS[(quad * 4 + r) * 260 + wave * 16 + l15] = scale * acc[r];
    __syncthreads();

    // per-row partials: wave w = row r0+w; 4 floats/lane over 256 cols
    {
        const float4 f = *(const float4*)&logitsS[wave * 260 + lane * 4];
        float mx = fmaxf(fmaxf(f.x, f.y), fmaxf(f.z, f.w));
#pragma unroll
        for (int s = 32; s; s >>= 1) mx = fmaxf(mx, __shfl_xor(mx, s, 64));
        float sum = __expf(f.x - mx) + __expf(f.y - mx) +
                    __expf(f.z - mx) + __expf(f.w - mx);
#pragma unroll
        for (int s = 32; s; s >>= 1) sum += __shfl_xor(sum, s, 64);
        if (lane == 0) {
            atomicExch(&pmax[(r0 + wave) * 4 + chunk], mx);
            atomicExch(&psum[(r0 + wave) * 4 + chunk], sum);
        }
    }

    // labels: waves 0..3 handle row j = r0 + chunk*4 + wave (R7 verbatim)
    if (wave < 4) {
        const int j = r0 + chunk * 4 + wave;
        const float2 sj = *(const float2*)(img + (size_t)j * DIM);
        int lo = -1;
        int label = j;
        for (;;) {
            int cand = BATCH;
#pragma unroll
            for (int it = 0; it < 16; ++it) {
                const int i = lane + it * 64;          // always < 1024, in-bounds
                const float2 si = *(const float2*)(img + (size_t)i * DIM);
                if (i < j && i > lo && si.x == sj.x && si.y == sj.y)
                    cand = min(cand, i);
            }
#pragma unroll
            for (int s = 32; s; s >>= 1) cand = min(cand, __shfl_xor(cand, s, 64));
            if (cand >= j) break;                      // no candidate -> label = j
            const float4* rpm = (const float4*)(img + (size_t)cand * DIM);
            const float4* rpj = (const float4*)(img + (size_t)j * DIM);
            bool eq = true;
#pragma unroll
            for (int cc = 0; cc < 3; ++cc) {
                float4 vm = rpm[cc * 64 + lane];
                float4 vj = rpj[cc * 64 + lane];
                eq = eq && (vm.x == vj.x) && (vm.y == vj.y) &&
                     (vm.z == vj.z) && (vm.w == vj.w);
            }
            if (__all(eq)) { label = cand; break; }
            lo = cand;                                 // false positive: rescan above it
        }

        // exact fp32 label logit: scale * dot(img[j], txt[label])
        const float4* aj = (const float4*)(img + (size_t)j * DIM);
        const float4* bl = (const float4*)(txt + (size_t)label * DIM);
        float s = 0.0f;
#pragma unroll
        for (int cc = 0; cc < 3; ++cc) {
            const float4 va = aj[cc * 64 + lane];
            const float4 vb = bl[cc * 64 + lane];
            s += va.x * vb.x + va.y * vb.y + va.z * vb.z + va.w * vb.w;
        }
#pragma unroll
        for (int m = 32; m; m >>= 1) s += __shfl_xor(s, m, 64);
        if (lane == 0) atomicExch(&lval[j], scale * s);
    }

    // last-block tail (R7-verified, no release fence, no spins)
    __syncthreads();
    if (tid == 0)
        isLast = (atomicAdd(tailcnt, 1) == (int)gridDim.x - 1) ? 1 : 0;
    __syncthreads();
    if (!isLast) return;
    __threadfence();   // acquire: invalidate local caches before remote reads

    // thread t combines row t: lse from 4 chunk partials minus label logit
    {
        const float4 m4 = *(const float4*)&pmax[tid * 4];
        const float4 s4 = *(const float4*)&psum[tid * 4];
        const float lv = lval[tid];
        const float gmax = fmaxf(fmaxf(m4.x, m4.y), fmaxf(m4.z, m4.w));
        const float ss = s4.x * __expf(m4.x - gmax) + s4.y * __expf(m4.y - gmax)
                       + s4.z * __expf(m4.z - gmax) + s4.w * __expf(m4.w - gmax);
        float loss = gmax + __logf(ss) - lv;
#pragma unroll
        for (int m = 32; m; m >>= 1) loss += __shfl_xor(loss, m, 64);
        if (lane == 0) part[wave] = loss;
        __syncthreads();
        if (tid == 0) {
            float tot = 0.0f;
#pragma unroll
            for (int w = 0; w < 16; ++w) tot += part[w];
            out[0] = tot * (1.0f / BATCH);
        }
    }
}

extern "C" void kernel_launch(void* const* d_in, const int* in_sizes, int n_in,
                              void* d_out, int out_size, void* d_ws, size_t ws_size,
                              hipStream_t stream) {
    const float* img   = (const float*)d_in[0];
    const float* txt   = (const float*)d_in[1];
    const float* scale = (const float*)d_in[2];
    float* out = (float*)d_out;
    char* ws = (char*)d_ws;

    int*   tailcnt = (int*)(ws + WS_TAIL);
    float* pmax    = (float*)(ws + WS_PMAX);
    float* psum    = (float*)(ws + WS_PSUM);
    float* lval    = (float*)(ws + WS_LVAL);
    unsigned short* txtB = (unsigned short*)(ws + WS_TXTB);

    void* args[] = {(void*)&img, (void*)&txt, (void*)&scale, (void*)&txtB,
                    (void*)&pmax, (void*)&psum, (void*)&lval,
                    (void*)&tailcnt, (void*)&out};
    hipLaunchCooperativeKernel((void*)coop_kernel, dim3(256), dim3(1024),
                               args, 0, stream);
}

// Round 14
// 78.264 us; speedup vs baseline: 1.4434x; 1.4434x over previous
//
#include <hip/hip_runtime.h>
#include <stdint.h>

#define BATCH 1024
#define DIM 768

typedef unsigned long long u64;
typedef __attribute__((ext_vector_type(8))) short short8;  // 8 bf16 = 4 VGPRs
typedef __attribute__((ext_vector_type(4))) float f32x4;

// Workspace layout (bytes):
//   [0]      int   tailcnt             (zeroed by prep block 0)
//   [4096]   float pmax[1024*4]        (16 KB) per-row per-chunk max
//   [20480]  float psum[1024*4]        (16 KB) per-row per-chunk sumexp
//   [36864]  float lval[1024]          (4 KB)  exact fp32 label logit per row
//   [49152]  ushort txtB[1024*768]     (1.5 MB) bf16, MFMA B-frag order
// B-frag order: off(col,k) = ((k>>5)*64 + (col>>4))*512 + ((k>>3)&3)*128
//                            + (col&15)*8 + (k&7)
// -> a wave's 16x16x32 B-fragment is one contiguous 1 KB run (16 B/lane).
#define WS_TAIL     0
#define WS_PMAX  4096
#define WS_PSUM 20480
#define WS_LVAL 36864
#define WS_TXTB 49152

__device__ __forceinline__ unsigned short to_bf16(float x) {
    unsigned int u = __float_as_uint(x);
    return (unsigned short)((u + 0x7FFFu + ((u >> 16) & 1u)) >> 16);  // RNE
}

// ---------------------------------------------------------------------------
// K1: txt fp32 -> bf16 B-frag order + zero tailcnt. 256 blocks x 256 threads.
// (R7-proven, measured 77.88 us total, absmax 0.0.)
// ---------------------------------------------------------------------------
__global__ __launch_bounds__(256) void prep_kernel(
        const float* __restrict__ txt, int* __restrict__ tailcnt,
        unsigned short* __restrict__ txtB) {
    if (blockIdx.x == 0 && threadIdx.x == 0) { *tailcnt = 0; }
    const int wave = threadIdx.x >> 6;
    const int lane = threadIdx.x & 63;

    for (int i = wave; i < 6; i += 4) {
        const int G  = blockIdx.x * 6 + i;
        const int tt = G / 24;        // col-tile 0..63
        const int g  = G - tt * 24;   // k-group 0..23
        const int col = tt * 16 + (lane & 15);
        const int k0  = g * 32 + (lane >> 4) * 8;
        const float4 va = *(const float4*)(txt + (size_t)col * DIM + k0);
        const float4 vb = *(const float4*)(txt + (size_t)col * DIM + k0 + 4);
        short8 hv = {(short)to_bf16(va.x), (short)to_bf16(va.y),
                     (short)to_bf16(va.z), (short)to_bf16(va.w),
                     (short)to_bf16(vb.x), (short)to_bf16(vb.y),
                     (short)to_bf16(vb.z), (short)to_bf16(vb.w)};
        *(short8*)(txtB + (size_t)(g * 64 + tt) * 512 + lane * 8) = hv;
    }
}

// ---------------------------------------------------------------------------
// K2: MFMA GEMM + softmax partials + labels + label logit + last-block
// combine. 256 blocks x 1024 thr. Block = 16 rows x 256 cols (row-group
// b>>2, col-chunk b&3). R7-verbatim:
//   - labels via float2-signature scan (absmax 0.0 across 5 rounds)
//   - no per-block release threadfence (R7-verified ordering: device-scope
//     atomicExch publishes complete at the coherent point before the
//     __syncthreads vmcnt(0) drain lets tid0 issue the tailcnt RMW)
//   - counter-based last-block tail, acquire fence on consumer only
//   - no spin loops anywhere
// ---------------------------------------------------------------------------
__global__ __launch_bounds__(1024) void gemm_fused(
        const float* __restrict__ img, const float* __restrict__ txt,
        const float* __restrict__ scale_p, const unsigned short* __restrict__ txtB,
        float* __restrict__ pmax, float* __restrict__ psum,
        float* __restrict__ lval, int* __restrict__ tailcnt,
        float* __restrict__ out) {
    __shared__ unsigned short Ahi[16 * DIM];   // 24 KB, A-frag order
    __shared__ float logitsS[16 * 260];        // 16.6 KB (+4 pad vs bank stride)
    __shared__ int isLast;
    __shared__ float part[16];

    const int tid  = threadIdx.x;
    const int wave = tid >> 6;
    const int lane = tid & 63;
    const int quad = lane >> 4;
    const int l15  = lane & 15;
    const int r0    = (blockIdx.x >> 2) * 16;
    const int chunk = blockIdx.x & 3;

    // stage A: wave w converts img row r0+w into frag order
    {
        const float* ir = img + (size_t)(r0 + wave) * DIM;
#pragma unroll
        for (int j = 0; j < 12; ++j) {
            const int k = lane + j * 64;
            Ahi[((k >> 3) * 16 + wave) * 8 + (k & 7)] = to_bf16(ir[k]);
        }
    }
    __syncthreads();

    // k-loop: wave's global col-tile t, one MFMA per 32-k step; B-frags are
    // contiguous 1 KB runs in txtB (L2-resident) — no k-loop barriers.
    const int t = chunk * 16 + wave;
    const int foff = quad * 128 + l15 * 8;
    f32x4 acc = {0.f, 0.f, 0.f, 0.f};
#pragma unroll
    for (int kk = 0; kk < 24; ++kk) {
        const short8 a = *(const short8*)&Ahi[kk * 512 + foff];
        const short8 b = *(const short8*)(txtB + (size_t)(kk * 64 + t) * 512 + foff);
        acc = __builtin_amdgcn_mfma_f32_16x16x32_bf16(a, b, acc, 0, 0, 0);
    }

    // C layout: col = l15, row = quad*4 + r  [verified, absmax 0.0]
    const float scale = scale_p[0];
#pragma unroll
    for (int r = 0; r < 4; ++r)
        logitsS[(quad * 4 + r) * 260 + wave * 16 + l15] = scale * acc[r];
    __syncthreads();

    // per-row partials: wave w = row r0+w; 4 floats/lane over 256 cols
    {
        const float4 f = *(const float4*)&logitsS[wave * 260 + lane * 4];
        float mx = fmaxf(fmaxf(f.x, f.y), fmaxf(f.z, f.w));
#pragma unroll
        for (int s = 32; s; s >>= 1) mx = fmaxf(mx, __shfl_xor(mx, s, 64));
        float sum = __expf(f.x - mx) + __expf(f.y - mx) +
                    __expf(f.z - mx) + __expf(f.w - mx);
#pragma unroll
        for (int s = 32; s; s >>= 1) sum += __shfl_xor(sum, s, 64);
        if (lane == 0) {
            atomicExch(&pmax[(r0 + wave) * 4 + chunk], mx);
            atomicExch(&psum[(r0 + wave) * 4 + chunk], sum);
        }
    }

    // labels: waves 0..3 handle row j = r0 + chunk*4 + wave.
    // Filter: float2 signature at row start (float compares -> can never
    // exclude a true float== match). Decide: exact float== verify.
    if (wave < 4) {
        const int j = r0 + chunk * 4 + wave;
        const float2 sj = *(const float2*)(img + (size_t)j * DIM);
        int lo = -1;
        int label = j;
        for (;;) {
            int cand = BATCH;
#pragma unroll
            for (int it = 0; it < 16; ++it) {
                const int i = lane + it * 64;          // always < 1024, in-bounds
                const float2 si = *(const float2*)(img + (size_t)i * DIM);
                if (i < j && i > lo && si.x == sj.x && si.y == sj.y)
                    cand = min(cand, i);
            }
#pragma unroll
            for (int s = 32; s; s >>= 1) cand = min(cand, __shfl_xor(cand, s, 64));
            if (cand >= j) break;                      // no candidate -> label = j
            const float4* rpm = (const float4*)(img + (size_t)cand * DIM);
            const float4* rpj = (const float4*)(img + (size_t)j * DIM);
            bool eq = true;
#pragma unroll
            for (int cc = 0; cc < 3; ++cc) {
                float4 vm = rpm[cc * 64 + lane];
                float4 vj = rpj[cc * 64 + lane];
                eq = eq && (vm.x == vj.x) && (vm.y == vj.y) &&
                     (vm.z == vj.z) && (vm.w == vj.w);
            }
            if (__all(eq)) { label = cand; break; }
            lo = cand;                                 // false positive: rescan above it
        }

        // exact fp32 label logit: scale * dot(img[j], txt[label])
        const float4* aj = (const float4*)(img + (size_t)j * DIM);
        const float4* bl = (const float4*)(txt + (size_t)label * DIM);
        float s = 0.0f;
#pragma unroll
        for (int cc = 0; cc < 3; ++cc) {
            const float4 va = aj[cc * 64 + lane];
            const float4 vb = bl[cc * 64 + lane];
            s += va.x * vb.x + va.y * vb.y + va.z * vb.z + va.w * vb.w;
        }
#pragma unroll
        for (int m = 32; m; m >>= 1) s += __shfl_xor(s, m, 64);
        if (lane == 0) atomicExch(&lval[j], scale * s);
    }

    // last-block tail (R7-verified, no release fence, no spins)
    __syncthreads();
    if (tid == 0)
        isLast = (atomicAdd(tailcnt, 1) == (int)gridDim.x - 1) ? 1 : 0;
    __syncthreads();
    if (!isLast) return;
    __threadfence();   // acquire: invalidate local caches before remote reads

    // thread t combines row t: lse from 4 chunk partials minus label logit
    {
        const float4 m4 = *(const float4*)&pmax[tid * 4];
        const float4 s4 = *(const float4*)&psum[tid * 4];
        const float lv = lval[tid];
        const float gmax = fmaxf(fmaxf(m4.x, m4.y), fmaxf(m4.z, m4.w));
        const float ss = s4.x * __expf(m4.x - gmax) + s4.y * __expf(m4.y - gmax)
                       + s4.z * __expf(m4.z - gmax) + s4.w * __expf(m4.w - gmax);
        float loss = gmax + __logf(ss) - lv;
#pragma unroll
        for (int m = 32; m; m >>= 1) loss += __shfl_xor(loss, m, 64);
        if (lane == 0) part[wave] = loss;
        __syncthreads();
        if (tid == 0) {
            float tot = 0.0f;
#pragma unroll
            for (int w = 0; w < 16; ++w) tot += part[w];
            out[0] = tot * (1.0f / BATCH);
        }
    }
}

extern "C" void kernel_launch(void* const* d_in, const int* in_sizes, int n_in,
                              void* d_out, int out_size, void* d_ws, size_t ws_size,
                              hipStream_t stream) {
    const float* img   = (const float*)d_in[0];
    const float* txt   = (const float*)d_in[1];
    const float* scale = (const float*)d_in[2];
    float* out = (float*)d_out;
    char* ws = (char*)d_ws;

    int*   tailcnt = (int*)(ws + WS_TAIL);
    float* pmax    = (float*)(ws + WS_PMAX);
    float* psum    = (float*)(ws + WS_PSUM);
    float* lval    = (float*)(ws + WS_LVAL);
    unsigned short* txtB = (unsigned short*)(ws + WS_TXTB);

    prep_kernel<<<256, 256, 0, stream>>>(txt, tailcnt, txtB);
    gemm_fused<<<256, 1024, 0, stream>>>(img, txt, scale, txtB,
                                         pmax, psum, lval, tailcnt, out);
}